// Round 4
// baseline (375.729 us; speedup 1.0000x reference)
//
#include <hip/hip_runtime.h>
#include <hip/hip_bf16.h>

// Single-head causal attention. Inputs fp32, OUTPUT fp32 (R3 forensics: two
// independent correct attention kernels gave identical absmax error == the
// signature of bf16-written-into-fp32-read output buffer).
// B=4, T=4096, C=2048, HS=128.
//
// Pipeline (all on `stream`):
//   1) transpose_kernel<float> x3 : Wq/Wk/Wv fp32 [C][HS] -> bf16 WT [HS][C]
//   2) qkv_gemm_kernel            : q,k,v = bf16(x) @ WT (fp32 x staged->bf16 LDS)
//   3) transpose_kernel<u16>      : v [B][T][HS] -> vT [B][HS][T]
//   4) flash_attn_kernel          : online-softmax flash, BQ=64, BKV=64, fp32 out

#define B_  4
#define T_  4096
#define C_  2048
#define HS_ 128

typedef unsigned short u16;
typedef __attribute__((ext_vector_type(8))) short short8;
typedef __attribute__((ext_vector_type(4))) float floatx4;

static __device__ __forceinline__ u16 f2bf(float x) {
  union { float f; unsigned u; } c; c.f = x;
  unsigned r = 0x7fffu + ((c.u >> 16) & 1u);
  return (u16)((c.u + r) >> 16);
}
static __device__ __forceinline__ u16 cvt_elem(float x) { return f2bf(x); }
static __device__ __forceinline__ u16 cvt_elem(u16 x) { return x; }

// ---------------------------------------------------------------- transpose
// src[R][C] -> dst[C][R] (fp32->bf16 convert for float src), 32x32 tiles.
template <typename ST>
__global__ __launch_bounds__(256) void transpose_kernel(
    const ST* __restrict__ src, u16* __restrict__ dst, int R, int C) {
  __shared__ u16 tile[32][33];
  size_t moff = (size_t)blockIdx.z * (size_t)R * (size_t)C;
  src += moff; dst += moff;
  int c0 = blockIdx.x * 32, r0 = blockIdx.y * 32;
  int tx = threadIdx.x, ty = threadIdx.y;  // block (32, 8)
#pragma unroll
  for (int i = 0; i < 4; ++i)
    tile[ty + 8 * i][tx] = cvt_elem(src[(size_t)(r0 + ty + 8 * i) * C + (c0 + tx)]);
  __syncthreads();
#pragma unroll
  for (int i = 0; i < 4; ++i)
    dst[(size_t)(c0 + ty + 8 * i) * R + (r0 + tx)] = tile[tx][ty + 8 * i];
}

// ---------------------------------------------------------------- QKV GEMM
// C[16384,128] = bf16(X) @ W, blockIdx.y selects q/k/v.
// 128(M) x 128(N) x 64(K) tiles; 4 waves 2x2, each 64x64 (4x4 frags).
#define GBM 128
#define GBK 64
#define LPAD 72  // 64+8 pad: row stride 144 B, ds_read_b128 stays 16B-aligned

__global__ __launch_bounds__(256) void qkv_gemm_kernel(
    const float* __restrict__ X, const u16* __restrict__ WT3,
    u16* __restrict__ qkv) {
  __shared__ u16 Xs[GBM][LPAD];   // [m][k]
  __shared__ u16 Ws[HS_][LPAD];   // [n][k]
  int z = blockIdx.y;
  const u16* Wt = WT3 + (size_t)z * HS_ * C_;
  u16* outp = qkv + (size_t)z * ((size_t)B_ * T_ * HS_);
  int t = threadIdx.x;
  int wv = t >> 6, lane = t & 63;
  int l15 = lane & 15, hi = lane >> 4;
  int wm = (wv & 1) * 64, wn = (wv >> 1) * 64;
  size_t mbase = (size_t)blockIdx.x * GBM;

  floatx4 acc[4][4];
#pragma unroll
  for (int i = 0; i < 4; ++i)
#pragma unroll
    for (int j = 0; j < 4; ++j) acc[i][j] = (floatx4){0.f, 0.f, 0.f, 0.f};

  for (int kt = 0; kt < C_ / GBK; ++kt) {
#pragma unroll
    for (int i = 0; i < 4; ++i) {
      int id = i * 256 + t;
      int m = id >> 3, c = id & 7;
      const float* sp = &X[(mbase + m) * C_ + kt * GBK + c * 8];
      short8 v;
#pragma unroll
      for (int j = 0; j < 8; ++j) v[j] = (short)f2bf(sp[j]);
      *(short8*)&Xs[m][c * 8] = v;
    }
#pragma unroll
    for (int i = 0; i < 4; ++i) {
      int id = i * 256 + t;
      int n = id >> 3, c = id & 7;
      *(short8*)&Ws[n][c * 8] =
          *(const short8*)&Wt[(size_t)n * C_ + kt * GBK + c * 8];
    }
    __syncthreads();
#pragma unroll
    for (int ks = 0; ks < 2; ++ks) {
      short8 af[4], bf[4];
#pragma unroll
      for (int mt = 0; mt < 4; ++mt)
        af[mt] = *(const short8*)&Xs[wm + mt * 16 + l15][ks * 32 + hi * 8];
#pragma unroll
      for (int nt = 0; nt < 4; ++nt)
        bf[nt] = *(const short8*)&Ws[wn + nt * 16 + l15][ks * 32 + hi * 8];
#pragma unroll
      for (int mt = 0; mt < 4; ++mt)
#pragma unroll
        for (int nt = 0; nt < 4; ++nt)
          acc[mt][nt] = __builtin_amdgcn_mfma_f32_16x16x32_bf16(
              af[mt], bf[nt], acc[mt][nt], 0, 0, 0);
    }
    __syncthreads();
  }
  // C/D layout: col=lane&15, row=(lane>>4)*4+reg
#pragma unroll
  for (int mt = 0; mt < 4; ++mt)
#pragma unroll
    for (int nt = 0; nt < 4; ++nt)
#pragma unroll
      for (int r = 0; r < 4; ++r) {
        size_t row = mbase + wm + mt * 16 + hi * 4 + r;
        int col = wn + nt * 16 + l15;
        outp[row * HS_ + col] = f2bf(acc[mt][nt][r]);
      }
}

// ---------------------------------------------------------------- flash attention
// One block per (64-row q-tile, batch). Wave w owns q rows w*16..+15.
// Online softmax in exp2 domain; P round-trips LDS (C-layout -> A-layout).
#define BQ 64
#define BKV 64

__global__ __launch_bounds__(256) void flash_attn_kernel(
    const u16* __restrict__ q, const u16* __restrict__ k,
    const u16* __restrict__ vT, float* __restrict__ out) {
  __shared__ u16 Ks[BKV][136];  // [key_token][d], pad 128->136
  __shared__ u16 Vs[HS_][72];   // [d][key_token], pad 64->72
  __shared__ u16 Ps[BQ][72];    // [q_row][key_token], pad 64->72
  int b = blockIdx.y, qb = blockIdx.x;
  int t = threadIdx.x;
  int wv = t >> 6, lane = t & 63, l15 = lane & 15, hi = lane >> 4;

  const float sc = 0.08838834764831845f * 1.4426950408889634f;  // 1/sqrt(128)*log2(e)

  short8 qf[4];
  {
    const u16* qrow = q + (size_t)(b * T_ + qb * BQ + wv * 16 + l15) * HS_;
#pragma unroll
    for (int ks = 0; ks < 4; ++ks)
      qf[ks] = *(const short8*)(qrow + ks * 32 + hi * 8);
  }

  floatx4 of[8];
#pragma unroll
  for (int dt = 0; dt < 8; ++dt) of[dt] = (floatx4){0.f, 0.f, 0.f, 0.f};
  float m_run[4], l_run[4];
#pragma unroll
  for (int r = 0; r < 4; ++r) { m_run[r] = -__builtin_inff(); l_run[r] = 0.f; }

  const u16* kbase = k + (size_t)b * T_ * HS_;
  const u16* vbase = vT + (size_t)b * HS_ * T_;

  for (int kb = 0; kb <= qb; ++kb) {
#pragma unroll
    for (int i = 0; i < 4; ++i) {
      int id = i * 256 + t;
      int n = id >> 4, c = id & 15;
      *(short8*)&Ks[n][c * 8] =
          *(const short8*)&kbase[(size_t)(kb * BKV + n) * HS_ + c * 8];
    }
#pragma unroll
    for (int i = 0; i < 4; ++i) {
      int id = i * 256 + t;
      int d = id >> 3, c = id & 7;
      *(short8*)&Vs[d][c * 8] =
          *(const short8*)&vbase[(size_t)d * T_ + kb * BKV + c * 8];
    }
    __syncthreads();

    // S = Q K^T (16 rows x 64 cols per wave)
    floatx4 sf[4];
#pragma unroll
    for (int nt = 0; nt < 4; ++nt) {
      floatx4 s = (floatx4){0.f, 0.f, 0.f, 0.f};
#pragma unroll
      for (int ks = 0; ks < 4; ++ks) {
        short8 bfrag = *(const short8*)&Ks[nt * 16 + l15][ks * 32 + hi * 8];
        s = __builtin_amdgcn_mfma_f32_16x16x32_bf16(qf[ks], bfrag, s, 0, 0, 0);
      }
      sf[nt] = s;
    }

    float sv[4][4];
    if (kb == qb) {
#pragma unroll
      for (int nt = 0; nt < 4; ++nt) {
        int col = nt * 16 + l15;
#pragma unroll
        for (int r = 0; r < 4; ++r) {
          int row = wv * 16 + hi * 4 + r;
          sv[nt][r] = (col <= row) ? sf[nt][r] * sc : -__builtin_inff();
        }
      }
    } else {
#pragma unroll
      for (int nt = 0; nt < 4; ++nt)
#pragma unroll
        for (int r = 0; r < 4; ++r) sv[nt][r] = sf[nt][r] * sc;
    }

    // online softmax (row stats per 16-lane group; rows = hi*4+r)
    float mt4[4], alpha[4];
#pragma unroll
    for (int r = 0; r < 4; ++r)
      mt4[r] = fmaxf(fmaxf(sv[0][r], sv[1][r]), fmaxf(sv[2][r], sv[3][r]));
#pragma unroll
    for (int off = 1; off < 16; off <<= 1)
#pragma unroll
      for (int r = 0; r < 4; ++r)
        mt4[r] = fmaxf(mt4[r], __shfl_xor(mt4[r], off));
#pragma unroll
    for (int r = 0; r < 4; ++r) {
      float mn = fmaxf(m_run[r], mt4[r]);
      alpha[r] = exp2f(m_run[r] - mn);
      m_run[r] = mn;
    }
    float pv[4][4], lt[4];
#pragma unroll
    for (int nt = 0; nt < 4; ++nt)
#pragma unroll
      for (int r = 0; r < 4; ++r) pv[nt][r] = exp2f(sv[nt][r] - m_run[r]);
#pragma unroll
    for (int r = 0; r < 4; ++r)
      lt[r] = (pv[0][r] + pv[1][r]) + (pv[2][r] + pv[3][r]);
#pragma unroll
    for (int off = 1; off < 16; off <<= 1)
#pragma unroll
      for (int r = 0; r < 4; ++r) lt[r] += __shfl_xor(lt[r], off);
#pragma unroll
    for (int r = 0; r < 4; ++r) l_run[r] = l_run[r] * alpha[r] + lt[r];
#pragma unroll
    for (int dt = 0; dt < 8; ++dt)
#pragma unroll
      for (int r = 0; r < 4; ++r) of[dt][r] *= alpha[r];

    // P: C-layout -> LDS -> A-layout (wave-local rows; lgkmcnt drain suffices)
#pragma unroll
    for (int nt = 0; nt < 4; ++nt)
#pragma unroll
      for (int r = 0; r < 4; ++r)
        Ps[wv * 16 + hi * 4 + r][nt * 16 + l15] = f2bf(pv[nt][r]);
    __asm__ volatile("s_waitcnt lgkmcnt(0)" ::: "memory");

    // O += P @ V
#pragma unroll
    for (int ks2 = 0; ks2 < 2; ++ks2) {
      short8 af = *(const short8*)&Ps[wv * 16 + l15][ks2 * 32 + hi * 8];
#pragma unroll
      for (int dt = 0; dt < 8; ++dt) {
        short8 bfrag = *(const short8*)&Vs[dt * 16 + l15][ks2 * 32 + hi * 8];
        of[dt] = __builtin_amdgcn_mfma_f32_16x16x32_bf16(af, bfrag, of[dt], 0, 0, 0);
      }
    }
    __syncthreads();
  }

  // epilogue: y = O / l, fp32 out
  float rl[4];
#pragma unroll
  for (int r = 0; r < 4; ++r) rl[r] = 1.0f / l_run[r];
#pragma unroll
  for (int dt = 0; dt < 8; ++dt)
#pragma unroll
    for (int r = 0; r < 4; ++r) {
      size_t row = (size_t)(b * T_ + qb * BQ + wv * 16 + hi * 4 + r);
      out[row * HS_ + dt * 16 + l15] = of[dt][r] * rl[r];
    }
}

// ---------------------------------------------------------------- launch
extern "C" void kernel_launch(void* const* d_in, const int* in_sizes, int n_in,
                              void* d_out, int out_size, void* d_ws, size_t ws_size,
                              hipStream_t stream) {
  const float* x  = (const float*)d_in[0];
  const float* Wq = (const float*)d_in[1];
  const float* Wk = (const float*)d_in[2];
  const float* Wv = (const float*)d_in[3];
  float* out = (float*)d_out;   // fp32 output per reference dtype

  u16* ws = (u16*)d_ws;
  const size_t wtsz  = (size_t)HS_ * C_;         // 262144 elems per weight
  const size_t qkvsz = (size_t)B_ * T_ * HS_;    // 2097152 elems each
  u16* WT = ws;                // [3][HS][C] bf16
  u16* qv = WT + 3 * wtsz;     // q [B][T][HS]
  u16* kv = qv + qkvsz;        // k [B][T][HS]
  u16* vv = kv + qkvsz;        // v [B][T][HS]
  u16* vT = vv + qkvsz;        // vT [B][HS][T]
  // total ws usage ~18.4 MB

  dim3 tb(32, 8);
  transpose_kernel<float><<<dim3(HS_ / 32, C_ / 32, 1), tb, 0, stream>>>(Wq, WT + 0 * wtsz, C_, HS_);
  transpose_kernel<float><<<dim3(HS_ / 32, C_ / 32, 1), tb, 0, stream>>>(Wk, WT + 1 * wtsz, C_, HS_);
  transpose_kernel<float><<<dim3(HS_ / 32, C_ / 32, 1), tb, 0, stream>>>(Wv, WT + 2 * wtsz, C_, HS_);

  qkv_gemm_kernel<<<dim3((B_ * T_) / GBM, 3), 256, 0, stream>>>(x, WT, qv);

  transpose_kernel<u16><<<dim3(HS_ / 32, T_ / 32, B_), tb, 0, stream>>>(vv, vT, T_, HS_);

  flash_attn_kernel<<<dim3(T_ / BQ, B_), 256, 0, stream>>>(qv, kv, vT, out);
}

// Round 5
// 352.346 us; speedup vs baseline: 1.0664x; 1.0664x over previous
//
#include <hip/hip_runtime.h>
#include <hip/hip_bf16.h>

// Single-head causal attention. fp32 in, fp32 out. B=4, T=4096, C=2048, HS=128.
//
// R5: split-KV flash decoding. R4's flash was occupancy-starved (5.9% occ,
// 256 blocks = 1/CU, triangular imbalance). Now: chunks of 16 KV-tiles per
// block -> 1024 blocks (3 co-resident/CU at 44KB LDS), partial (O,m,l) fp32
// to ws, tiny merge kernel. Fallback to monolithic flash if ws too small.

#define B_  4
#define T_  4096
#define C_  2048
#define HS_ 128

typedef unsigned short u16;
typedef __attribute__((ext_vector_type(8))) short short8;
typedef __attribute__((ext_vector_type(4))) float floatx4;

static __device__ __forceinline__ u16 f2bf(float x) {
  union { float f; unsigned u; } c; c.f = x;
  unsigned r = 0x7fffu + ((c.u >> 16) & 1u);
  return (u16)((c.u + r) >> 16);
}
static __device__ __forceinline__ u16 cvt_elem(float x) { return f2bf(x); }
static __device__ __forceinline__ u16 cvt_elem(u16 x) { return x; }

// ---------------------------------------------------------------- transpose
template <typename ST>
__global__ __launch_bounds__(256) void transpose_kernel(
    const ST* __restrict__ src, u16* __restrict__ dst, int R, int C) {
  __shared__ u16 tile[32][33];
  size_t moff = (size_t)blockIdx.z * (size_t)R * (size_t)C;
  src += moff; dst += moff;
  int c0 = blockIdx.x * 32, r0 = blockIdx.y * 32;
  int tx = threadIdx.x, ty = threadIdx.y;  // block (32, 8)
#pragma unroll
  for (int i = 0; i < 4; ++i)
    tile[ty + 8 * i][tx] = cvt_elem(src[(size_t)(r0 + ty + 8 * i) * C + (c0 + tx)]);
  __syncthreads();
#pragma unroll
  for (int i = 0; i < 4; ++i)
    dst[(size_t)(c0 + ty + 8 * i) * R + (r0 + tx)] = tile[tx][ty + 8 * i];
}

// ---------------------------------------------------------------- QKV GEMM
// (unchanged from R4 — profiled next round)
#define GBM 128
#define GBK 64
#define LPAD 72

__global__ __launch_bounds__(256) void qkv_gemm_kernel(
    const float* __restrict__ X, const u16* __restrict__ WT3,
    u16* __restrict__ qkv) {
  __shared__ u16 Xs[GBM][LPAD];
  __shared__ u16 Ws[HS_][LPAD];
  int z = blockIdx.y;
  const u16* Wt = WT3 + (size_t)z * HS_ * C_;
  u16* outp = qkv + (size_t)z * ((size_t)B_ * T_ * HS_);
  int t = threadIdx.x;
  int wv = t >> 6, lane = t & 63;
  int l15 = lane & 15, hi = lane >> 4;
  int wm = (wv & 1) * 64, wn = (wv >> 1) * 64;
  size_t mbase = (size_t)blockIdx.x * GBM;

  floatx4 acc[4][4];
#pragma unroll
  for (int i = 0; i < 4; ++i)
#pragma unroll
    for (int j = 0; j < 4; ++j) acc[i][j] = (floatx4){0.f, 0.f, 0.f, 0.f};

  for (int kt = 0; kt < C_ / GBK; ++kt) {
#pragma unroll
    for (int i = 0; i < 4; ++i) {
      int id = i * 256 + t;
      int m = id >> 3, c = id & 7;
      const float* sp = &X[(mbase + m) * C_ + kt * GBK + c * 8];
      short8 v;
#pragma unroll
      for (int j = 0; j < 8; ++j) v[j] = (short)f2bf(sp[j]);
      *(short8*)&Xs[m][c * 8] = v;
    }
#pragma unroll
    for (int i = 0; i < 4; ++i) {
      int id = i * 256 + t;
      int n = id >> 3, c = id & 7;
      *(short8*)&Ws[n][c * 8] =
          *(const short8*)&Wt[(size_t)n * C_ + kt * GBK + c * 8];
    }
    __syncthreads();
#pragma unroll
    for (int ks = 0; ks < 2; ++ks) {
      short8 af[4], bf[4];
#pragma unroll
      for (int mt = 0; mt < 4; ++mt)
        af[mt] = *(const short8*)&Xs[wm + mt * 16 + l15][ks * 32 + hi * 8];
#pragma unroll
      for (int nt = 0; nt < 4; ++nt)
        bf[nt] = *(const short8*)&Ws[wn + nt * 16 + l15][ks * 32 + hi * 8];
#pragma unroll
      for (int mt = 0; mt < 4; ++mt)
#pragma unroll
        for (int nt = 0; nt < 4; ++nt)
          acc[mt][nt] = __builtin_amdgcn_mfma_f32_16x16x32_bf16(
              af[mt], bf[nt], acc[mt][nt], 0, 0, 0);
    }
    __syncthreads();
  }
#pragma unroll
  for (int mt = 0; mt < 4; ++mt)
#pragma unroll
    for (int nt = 0; nt < 4; ++nt)
#pragma unroll
      for (int r = 0; r < 4; ++r) {
        size_t row = mbase + wm + mt * 16 + hi * 4 + r;
        int col = wn + nt * 16 + l15;
        outp[row * HS_ + col] = f2bf(acc[mt][nt][r]);
      }
}

// ---------------------------------------------------------------- flash core
#define BQ 64
#define BKV 64
#define CHUNK 16  // KV tiles per split-KV block (1024 keys)

// Shared body: processes kv tiles [kb0, kb1] for (b, qb). If WRITE_PARTIAL,
// writes unnormalized O + (m,l); else normalizes and writes fp32 out.
template <bool WRITE_PARTIAL>
static __device__ __forceinline__ void flash_body(
    const u16* __restrict__ q, const u16* __restrict__ k,
    const u16* __restrict__ vT, float* __restrict__ outO,
    float* __restrict__ Mp, float* __restrict__ Lp,
    int b, int qb, int kb0, int kb1, int slot) {
  __shared__ u16 Ks[BKV][136];
  __shared__ u16 Vs[HS_][72];
  __shared__ u16 Ps[BQ][72];
  int t = threadIdx.x;
  int wv = t >> 6, lane = t & 63, l15 = lane & 15, hi = lane >> 4;

  const float sc = 0.08838834764831845f * 1.4426950408889634f;

  short8 qf[4];
  {
    const u16* qrow = q + (size_t)(b * T_ + qb * BQ + wv * 16 + l15) * HS_;
#pragma unroll
    for (int ks = 0; ks < 4; ++ks)
      qf[ks] = *(const short8*)(qrow + ks * 32 + hi * 8);
  }

  floatx4 of[8];
#pragma unroll
  for (int dt = 0; dt < 8; ++dt) of[dt] = (floatx4){0.f, 0.f, 0.f, 0.f};
  float m_run[4], l_run[4];
#pragma unroll
  for (int r = 0; r < 4; ++r) { m_run[r] = -__builtin_inff(); l_run[r] = 0.f; }

  const u16* kbase = k + (size_t)b * T_ * HS_;
  const u16* vbase = vT + (size_t)b * HS_ * T_;

  for (int kb = kb0; kb <= kb1; ++kb) {
#pragma unroll
    for (int i = 0; i < 4; ++i) {
      int id = i * 256 + t;
      int n = id >> 4, c = id & 15;
      *(short8*)&Ks[n][c * 8] =
          *(const short8*)&kbase[(size_t)(kb * BKV + n) * HS_ + c * 8];
    }
#pragma unroll
    for (int i = 0; i < 4; ++i) {
      int id = i * 256 + t;
      int d = id >> 3, c = id & 7;
      *(short8*)&Vs[d][c * 8] =
          *(const short8*)&vbase[(size_t)d * T_ + kb * BKV + c * 8];
    }
    __syncthreads();

    floatx4 sf[4];
#pragma unroll
    for (int nt = 0; nt < 4; ++nt) {
      floatx4 s = (floatx4){0.f, 0.f, 0.f, 0.f};
#pragma unroll
      for (int ks = 0; ks < 4; ++ks) {
        short8 bfrag = *(const short8*)&Ks[nt * 16 + l15][ks * 32 + hi * 8];
        s = __builtin_amdgcn_mfma_f32_16x16x32_bf16(qf[ks], bfrag, s, 0, 0, 0);
      }
      sf[nt] = s;
    }

    float sv[4][4];
    if (kb == qb) {
#pragma unroll
      for (int nt = 0; nt < 4; ++nt) {
        int col = nt * 16 + l15;
#pragma unroll
        for (int r = 0; r < 4; ++r) {
          int row = wv * 16 + hi * 4 + r;
          sv[nt][r] = (col <= row) ? sf[nt][r] * sc : -__builtin_inff();
        }
      }
    } else {
#pragma unroll
      for (int nt = 0; nt < 4; ++nt)
#pragma unroll
        for (int r = 0; r < 4; ++r) sv[nt][r] = sf[nt][r] * sc;
    }

    float mt4[4], alpha[4];
#pragma unroll
    for (int r = 0; r < 4; ++r)
      mt4[r] = fmaxf(fmaxf(sv[0][r], sv[1][r]), fmaxf(sv[2][r], sv[3][r]));
#pragma unroll
    for (int off = 1; off < 16; off <<= 1)
#pragma unroll
      for (int r = 0; r < 4; ++r)
        mt4[r] = fmaxf(mt4[r], __shfl_xor(mt4[r], off));
#pragma unroll
    for (int r = 0; r < 4; ++r) {
      float mn = fmaxf(m_run[r], mt4[r]);
      alpha[r] = exp2f(m_run[r] - mn);
      m_run[r] = mn;
    }
    float pv[4][4], lt[4];
#pragma unroll
    for (int nt = 0; nt < 4; ++nt)
#pragma unroll
      for (int r = 0; r < 4; ++r) pv[nt][r] = exp2f(sv[nt][r] - m_run[r]);
#pragma unroll
    for (int r = 0; r < 4; ++r)
      lt[r] = (pv[0][r] + pv[1][r]) + (pv[2][r] + pv[3][r]);
#pragma unroll
    for (int off = 1; off < 16; off <<= 1)
#pragma unroll
      for (int r = 0; r < 4; ++r) lt[r] += __shfl_xor(lt[r], off);
#pragma unroll
    for (int r = 0; r < 4; ++r) l_run[r] = l_run[r] * alpha[r] + lt[r];
#pragma unroll
    for (int dt = 0; dt < 8; ++dt)
#pragma unroll
      for (int r = 0; r < 4; ++r) of[dt][r] *= alpha[r];

#pragma unroll
    for (int nt = 0; nt < 4; ++nt)
#pragma unroll
      for (int r = 0; r < 4; ++r)
        Ps[wv * 16 + hi * 4 + r][nt * 16 + l15] = f2bf(pv[nt][r]);
    __asm__ volatile("s_waitcnt lgkmcnt(0)" ::: "memory");

#pragma unroll
    for (int ks2 = 0; ks2 < 2; ++ks2) {
      short8 af = *(const short8*)&Ps[wv * 16 + l15][ks2 * 32 + hi * 8];
#pragma unroll
      for (int dt = 0; dt < 8; ++dt) {
        short8 bfrag = *(const short8*)&Vs[dt * 16 + l15][ks2 * 32 + hi * 8];
        of[dt] = __builtin_amdgcn_mfma_f32_16x16x32_bf16(af, bfrag, of[dt], 0, 0, 0);
      }
    }
    __syncthreads();
  }

  if (WRITE_PARTIAL) {
    float* Op = outO + (size_t)slot * (BQ * HS_);
#pragma unroll
    for (int dt = 0; dt < 8; ++dt)
#pragma unroll
      for (int r = 0; r < 4; ++r) {
        int row = wv * 16 + hi * 4 + r;
        Op[row * HS_ + dt * 16 + l15] = of[dt][r];
      }
    if (l15 == 0) {
#pragma unroll
      for (int r = 0; r < 4; ++r) {
        int row = wv * 16 + hi * 4 + r;
        Mp[slot * BQ + row] = m_run[r];
        Lp[slot * BQ + row] = l_run[r];
      }
    }
  } else {
    float rl[4];
#pragma unroll
    for (int r = 0; r < 4; ++r) rl[r] = 1.0f / l_run[r];
#pragma unroll
    for (int dt = 0; dt < 8; ++dt)
#pragma unroll
      for (int r = 0; r < 4; ++r) {
        size_t row = (size_t)(b * T_ + qb * BQ + wv * 16 + hi * 4 + r);
        outO[row * HS_ + dt * 16 + l15] = of[dt][r] * rl[r];
      }
  }
}

// split-KV partial: grid (64 qb, 4 chunk, 4 batch)
__global__ __launch_bounds__(256) void flash_partial_kernel(
    const u16* __restrict__ q, const u16* __restrict__ k,
    const u16* __restrict__ vT, float* __restrict__ Opart,
    float* __restrict__ Mpart, float* __restrict__ Lpart) {
  int qb = blockIdx.x, c = blockIdx.y, b = blockIdx.z;
  int kb0 = c * CHUNK;
  if (kb0 > qb) return;  // empty chunk
  int kb1 = min(qb, kb0 + CHUNK - 1);
  int slot = (b * (T_ / BQ) + qb) * 4 + c;
  flash_body<true>(q, k, vT, Opart, Mpart, Lpart, b, qb, kb0, kb1, slot);
}

// monolithic fallback (R4-proven): grid (64 qb, 4 batch)
__global__ __launch_bounds__(256) void flash_attn_kernel(
    const u16* __restrict__ q, const u16* __restrict__ k,
    const u16* __restrict__ vT, float* __restrict__ out) {
  int qb = blockIdx.x, b = blockIdx.y;
  flash_body<false>(q, k, vT, out, nullptr, nullptr, b, qb, 0, qb, 0);
}

// merge: grid (64 qb, 4 batch), 256 threads
__global__ __launch_bounds__(256) void flash_merge_kernel(
    const float* __restrict__ Opart, const float* __restrict__ Mpart,
    const float* __restrict__ Lpart, float* __restrict__ out) {
  __shared__ float w[4][BQ];
  __shared__ float invL[BQ];
  int qb = blockIdx.x, b = blockIdx.y;
  int t = threadIdx.x;
  int nch = qb / CHUNK + 1;  // 1..4
  int slot0 = (b * (T_ / BQ) + qb) * 4;

  if (t < BQ) {
    float mv[4], mmax = -__builtin_inff();
    for (int c = 0; c < nch; ++c) {
      mv[c] = Mpart[(slot0 + c) * BQ + t];
      mmax = fmaxf(mmax, mv[c]);
    }
    float L = 0.f;
    for (int c = 0; c < nch; ++c) {
      float wc = exp2f(mv[c] - mmax);
      w[c][t] = wc;
      L += wc * Lpart[(slot0 + c) * BQ + t];
    }
    invL[t] = 1.0f / L;
  }
  __syncthreads();

  size_t obase = ((size_t)(b * T_) + (size_t)qb * BQ) * HS_;
#pragma unroll
  for (int j = 0; j < 32; ++j) {
    int e = j * 256 + t;           // 0..8191
    int row = e >> 7;
    float acc = 0.f;
    for (int c = 0; c < nch; ++c)
      acc += w[c][row] * Opart[(size_t)(slot0 + c) * (BQ * HS_) + e];
    out[obase + e] = acc * invL[row];
  }
}

// ---------------------------------------------------------------- launch
extern "C" void kernel_launch(void* const* d_in, const int* in_sizes, int n_in,
                              void* d_out, int out_size, void* d_ws, size_t ws_size,
                              hipStream_t stream) {
  const float* x  = (const float*)d_in[0];
  const float* Wq = (const float*)d_in[1];
  const float* Wk = (const float*)d_in[2];
  const float* Wv = (const float*)d_in[3];
  float* out = (float*)d_out;

  u16* ws = (u16*)d_ws;
  const size_t wtsz  = (size_t)HS_ * C_;
  const size_t qkvsz = (size_t)B_ * T_ * HS_;
  u16* WT = ws;
  u16* qv = WT + 3 * wtsz;
  u16* kv = qv + qkvsz;
  u16* vv = kv + qkvsz;
  u16* vT = vv + qkvsz;
  const size_t base_bytes = (3 * wtsz + 4 * qkvsz) * sizeof(u16);  // 18,350,080

  const int NSLOT = B_ * (T_ / BQ) * 4;  // 1024
  float* Opart = (float*)((char*)d_ws + base_bytes);
  float* Mpart = Opart + (size_t)NSLOT * BQ * HS_;
  float* Lpart = Mpart + (size_t)NSLOT * BQ;
  const size_t split_bytes =
      base_bytes + ((size_t)NSLOT * BQ * HS_ + 2 * (size_t)NSLOT * BQ) * sizeof(float);

  dim3 tb(32, 8);
  transpose_kernel<float><<<dim3(HS_ / 32, C_ / 32, 1), tb, 0, stream>>>(Wq, WT + 0 * wtsz, C_, HS_);
  transpose_kernel<float><<<dim3(HS_ / 32, C_ / 32, 1), tb, 0, stream>>>(Wk, WT + 1 * wtsz, C_, HS_);
  transpose_kernel<float><<<dim3(HS_ / 32, C_ / 32, 1), tb, 0, stream>>>(Wv, WT + 2 * wtsz, C_, HS_);

  qkv_gemm_kernel<<<dim3((B_ * T_) / GBM, 3), 256, 0, stream>>>(x, WT, qv);

  transpose_kernel<u16><<<dim3(HS_ / 32, T_ / 32, B_), tb, 0, stream>>>(vv, vT, T_, HS_);

  if (ws_size >= split_bytes) {
    flash_partial_kernel<<<dim3(T_ / BQ, 4, B_), 256, 0, stream>>>(
        qv, kv, vT, Opart, Mpart, Lpart);
    flash_merge_kernel<<<dim3(T_ / BQ, B_), 256, 0, stream>>>(
        Opart, Mpart, Lpart, out);
  } else {
    flash_attn_kernel<<<dim3(T_ / BQ, B_), 256, 0, stream>>>(qv, kv, vT, out);
  }
}